// Round 4
// baseline (293.380 us; speedup 1.0000x reference)
//
#include <hip/hip_runtime.h>
#include <hip/hip_bf16.h>

#define B_     32
#define C_     256
#define T_     4096
#define NH_    8
#define DH_    64

// ---- fused: replicated-prep + logits + segment stats + weighted-x partials ----
// grid (8 jt, B_) x 512 threads. Each block owns j-segment [jt*512, jt*512+512)
// of batch b. x is streamed from HBM once (phase 1); phase 2 re-reads the same
// 512 KB slice from L2/L3. Outputs: per-segment LSE stats (m, sumexp) and
// part[b][jt][n][c] = sum_j exp(l-m_seg) * x[c,j].
#define XP_ 36
__global__ __launch_bounds__(512) void k_fused(
    const float* __restrict__ x, const float* __restrict__ query,
    const float* __restrict__ Wkv, const float* __restrict__ bkv,
    const float* __restrict__ Wq, const float* __restrict__ bq,
    float* __restrict__ stats, float* __restrict__ part) {
  const int jt = blockIdx.x;
  const int b  = blockIdx.y;
  const int t  = threadIdx.x;
  const int tj = t & 255;
  const int th = t >> 8;          // wave-uniform (waves 0-3: 0, 4-7: 1)

  __shared__ float qrow_s[C_];
  __shared__ float q_s[512];                       // q[n][d], bias included
  __shared__ float qws[C_ * NH_];                  // scaled qWt[c][n]
  __shared__ float qb_s[NH_];
  __shared__ float red[256 * 16];                  // 16 KB scratch
  __shared__ float sred[8][4];
  __shared__ float ssum[8][4];
  __shared__ float Msh[8];
  __shared__ __align__(16) float a_w[512][NH_];    // 16 KB: exp(l - m_seg)
  __shared__ __align__(16) float xs[C_ * XP_];     // 36.9 KB x subtile

  // ---------- replicated prep (weights L3-warm after first blocks) ----------
  if (t < 256) qrow_s[t] = query[(size_t)b * C_ + t];
  __syncthreads();
  {
    const int n = t >> 6, d = t & 63;               // t -> (n,d) exactly 512
    const float* wrow = Wq + (size_t)(n * DH_ + d) * C_;
    float s = bq[n * DH_ + d];
    #pragma unroll
    for (int c = 0; c < C_; c += 4) {
      float4 w = *(const float4*)(wrow + c);
      s += w.x * qrow_s[c] + w.y * qrow_s[c + 1] + w.z * qrow_s[c + 2] + w.w * qrow_s[c + 3];
    }
    q_s[t] = s;
  }
  __syncthreads();
  {
    const float scale = 0.125f;
    const int c = t & 255, ng = t >> 8;             // 2 head-groups of 4
    float o4[4];
    #pragma unroll
    for (int k = 0; k < 4; ++k) {
      const int n = ng * 4 + k;
      const float* wk = Wkv + (size_t)(n * DH_) * C_ + c;   // coalesced over c
      const float* qn = q_s + n * DH_;
      float s = 0.f;
      #pragma unroll 8
      for (int d = 0; d < DH_; ++d) s += qn[d] * wk[(size_t)d * C_];
      o4[k] = s * scale;
    }
    *(float4*)&qws[c * 8 + ng * 4] = make_float4(o4[0], o4[1], o4[2], o4[3]);
  }
  if (t < NH_) {
    const float* qn = q_s + t * DH_;
    const float* bk = bkv + t * DH_;
    float s = 0.f;
    #pragma unroll 8
    for (int d = 0; d < DH_; ++d) s += qn[d] * bk[d];
    qb_s[t] = s * 0.125f;
  }
  __syncthreads();

  // ---------- phase 1: logits (x from HBM, coalesced float2) ----------
  const int j = jt * 512 + tj * 2;
  const float* xb = x + ((size_t)b * C_ + th * 128) * T_ + j;

  float acc0[NH_], acc1[NH_];
  #pragma unroll
  for (int n = 0; n < NH_; ++n) {
    const float init = (th == 0) ? qb_s[n] : 0.f;
    acc0[n] = init; acc1[n] = init;
  }

  for (int c0 = 0; c0 < 128; c0 += 16) {
    float2 xv[16];
    #pragma unroll
    for (int cc = 0; cc < 16; ++cc)
      xv[cc] = *(const float2*)(xb + (size_t)(c0 + cc) * T_);
    #pragma unroll
    for (int cc = 0; cc < 16; ++cc) {
      const float4 w0 = *(const float4*)(qws + (th * 128 + c0 + cc) * 8);
      const float4 w1 = *(const float4*)(qws + (th * 128 + c0 + cc) * 8 + 4);
      acc0[0] += w0.x * xv[cc].x; acc1[0] += w0.x * xv[cc].y;
      acc0[1] += w0.y * xv[cc].x; acc1[1] += w0.y * xv[cc].y;
      acc0[2] += w0.z * xv[cc].x; acc1[2] += w0.z * xv[cc].y;
      acc0[3] += w0.w * xv[cc].x; acc1[3] += w0.w * xv[cc].y;
      acc0[4] += w1.x * xv[cc].x; acc1[4] += w1.x * xv[cc].y;
      acc0[5] += w1.y * xv[cc].x; acc1[5] += w1.y * xv[cc].y;
      acc0[6] += w1.z * xv[cc].x; acc1[6] += w1.z * xv[cc].y;
      acc0[7] += w1.w * xv[cc].x; acc1[7] += w1.w * xv[cc].y;
    }
  }

  if (th == 1) {
    float* r = red + tj * 16;
    #pragma unroll
    for (int n = 0; n < NH_; ++n) { r[n] = acc0[n]; r[8 + n] = acc1[n]; }
  }
  __syncthreads();
  if (th == 0) {
    const float* r = red + tj * 16;
    #pragma unroll
    for (int n = 0; n < NH_; ++n) { acc0[n] += r[n]; acc1[n] += r[8 + n]; }
  }

  // ---------- segment stats + weight table ----------
  #pragma unroll
  for (int n = 0; n < NH_; ++n) {
    float mv = fmaxf(acc0[n], acc1[n]);
    #pragma unroll
    for (int o = 32; o >= 1; o >>= 1) mv = fmaxf(mv, __shfl_xor(mv, o));
    if (th == 0 && (tj & 63) == 0) sred[n][tj >> 6] = mv;
  }
  __syncthreads();
  if (t < 8)
    Msh[t] = fmaxf(fmaxf(sred[t][0], sred[t][1]), fmaxf(sred[t][2], sred[t][3]));
  __syncthreads();
  float e0[NH_], e1[NH_];
  #pragma unroll
  for (int n = 0; n < NH_; ++n) {
    float sv = 0.f;
    if (th == 0) {
      e0[n] = expf(acc0[n] - Msh[n]);
      e1[n] = expf(acc1[n] - Msh[n]);
      sv = e0[n] + e1[n];
    }
    #pragma unroll
    for (int o = 32; o >= 1; o >>= 1) sv += __shfl_xor(sv, o);
    if (th == 0 && (tj & 63) == 0) ssum[n][tj >> 6] = sv;
  }
  if (th == 0) {   // unnormalized weights exp(l - m_seg); one-time b128 writes
    *(float4*)&a_w[tj * 2][0]     = make_float4(e0[0], e0[1], e0[2], e0[3]);
    *(float4*)&a_w[tj * 2][4]     = make_float4(e0[4], e0[5], e0[6], e0[7]);
    *(float4*)&a_w[tj * 2 + 1][0] = make_float4(e1[0], e1[1], e1[2], e1[3]);
    *(float4*)&a_w[tj * 2 + 1][4] = make_float4(e1[4], e1[5], e1[6], e1[7]);
  }
  __syncthreads();
  if (t < 8) {
    const float S = ssum[t][0] + ssum[t][1] + ssum[t][2] + ssum[t][3];
    float2 o; o.x = Msh[t]; o.y = S;
    *(float2*)(stats + ((size_t)(b * NH_ + t) * 8 + jt) * 2) = o;
  }

  // ---------- phase 2: part[n][c] = sum_j a_w[j][n] * x[c,j] (x from L2/L3) --
  const float* xb2 = x + (size_t)b * C_ * T_ + jt * 512;
  const int cr  = t >> 3;          // staging row 0..63
  const int jc  = (t & 7) * 4;     // staging j offset
  const int cc2 = t & 255;         // compute channel
  const int jh  = t >> 8;          // j-half of subtile

  float acc[NH_];
  #pragma unroll
  for (int n = 0; n < NH_; ++n) acc[n] = 0.f;

  for (int sIt = 0; sIt < 16; ++sIt) {
    const int js = sIt * 32;
    __syncthreads();
    #pragma unroll
    for (int p = 0; p < 4; ++p) {
      const int c = cr + p * 64;
      float4 vv = *(const float4*)(xb2 + (size_t)c * T_ + js + jc);
      *(float4*)&xs[c * XP_ + jc] = vv;
    }
    __syncthreads();
    #pragma unroll
    for (int g = 0; g < 4; ++g) {
      const int jj4 = jh * 16 + g * 4;
      const float4 xv = *(const float4*)&xs[cc2 * XP_ + jj4];
      #pragma unroll
      for (int q = 0; q < 4; ++q) {
        const float4 wlo = *(const float4*)&a_w[js + jj4 + q][0];  // broadcast
        const float4 whi = *(const float4*)&a_w[js + jj4 + q][4];
        const float xa = (q == 0) ? xv.x : (q == 1) ? xv.y : (q == 2) ? xv.z : xv.w;
        acc[0] += wlo.x * xa; acc[1] += wlo.y * xa;
        acc[2] += wlo.z * xa; acc[3] += wlo.w * xa;
        acc[4] += whi.x * xa; acc[5] += whi.y * xa;
        acc[6] += whi.z * xa; acc[7] += whi.w * xa;
      }
    }
  }

  __syncthreads();
  if (jh == 1) {
    *(float4*)&red[cc2 * 8]     = make_float4(acc[0], acc[1], acc[2], acc[3]);
    *(float4*)&red[cc2 * 8 + 4] = make_float4(acc[4], acc[5], acc[6], acc[7]);
  }
  __syncthreads();
  if (jh == 0) {
    float* pb = part + (((size_t)b * 8 + jt) * NH_) * C_;
    const float* r = &red[cc2 * 8];
    #pragma unroll
    for (int n = 0; n < NH_; ++n)
      pb[n * C_ + cc2] = acc[n] + r[n];
  }
}

// ---- tail: LSE segment combine + v-projection + fc, one block per batch ----
__global__ __launch_bounds__(512) void k_tail(
    const float* __restrict__ part, const float* __restrict__ stats,
    const float* __restrict__ Wkv, const float* __restrict__ bkv,
    const float* __restrict__ Wfc, const float* __restrict__ bfc,
    float* __restrict__ out) {
  const int b = blockIdx.x;
  const int t = threadIdx.x;
  __shared__ float sc[NH_][8];
  __shared__ float Ml[NH_], Sl[NH_];
  __shared__ float xa_s[NH_ * C_];
  __shared__ float ov_s[512];

  if (t < NH_) {
    const float* st = stats + (size_t)(b * NH_ + t) * 16;
    float M = -3.4e38f;
    #pragma unroll
    for (int k = 0; k < 8; ++k) M = fmaxf(M, st[2 * k]);
    float S = 0.f;
    #pragma unroll
    for (int k = 0; k < 8; ++k) S += st[2 * k + 1] * expf(st[2 * k] - M);
    Ml[t] = M; Sl[t] = 1.0f / S;
  }
  __syncthreads();
  if (t < 64) {
    const int n = t >> 3, k = t & 7;
    const float* st = stats + (size_t)(b * NH_ + n) * 16;
    sc[n][k] = expf(st[2 * k] - Ml[n]) * Sl[n];
  }
  __syncthreads();

  #pragma unroll
  for (int r = 0; r < 4; ++r) {
    const int idx = r * 512 + t;          // 0..2047 -> (n, c)
    const int n = idx >> 8, c = idx & 255;
    const float* pb = part + ((size_t)b * 8 * NH_) * C_ + n * C_ + c;
    float s = 0.f;
    #pragma unroll
    for (int k = 0; k < 8; ++k) s += sc[n][k] * pb[(size_t)k * NH_ * C_];
    xa_s[idx] = s;
  }
  __syncthreads();

  {
    const int o = t;                                // 0..511
    const float* wrow = Wkv + (size_t)(512 + o) * C_;
    const float* xa = &xa_s[(o >> 6) * C_];
    float s = bkv[512 + o];
    #pragma unroll 8
    for (int c = 0; c < C_; c += 4) {
      float4 w = *(const float4*)(wrow + c);
      s += w.x * xa[c] + w.y * xa[c + 1] + w.z * xa[c + 2] + w.w * xa[c + 3];
    }
    ov_s[o] = s;
  }
  __syncthreads();

  if (t < 256) {
    const float* wrow = Wfc + (size_t)t * 512;
    float s = bfc[t];
    #pragma unroll 8
    for (int o = 0; o < 512; o += 4) {
      float4 w = *(const float4*)(wrow + o);
      s += w.x * ov_s[o] + w.y * ov_s[o + 1] + w.z * ov_s[o + 2] + w.w * ov_s[o + 3];
    }
    out[(size_t)b * 256 + t] = fmaxf(s, 0.f);
  }
}

extern "C" void kernel_launch(void* const* d_in, const int* in_sizes, int n_in,
                              void* d_out, int out_size, void* d_ws, size_t ws_size,
                              hipStream_t stream) {
  const float* x     = (const float*)d_in[0];
  const float* query = (const float*)d_in[1];
  const float* Wkv   = (const float*)d_in[2];
  const float* bkv   = (const float*)d_in[3];
  const float* Wq    = (const float*)d_in[4];
  const float* bq    = (const float*)d_in[5];
  const float* Wfc   = (const float*)d_in[6];
  const float* bfc   = (const float*)d_in[7];
  float* out = (float*)d_out;
  float* ws  = (float*)d_ws;

  float* stats = ws;            // 32*8*8*2 = 4096 floats
  float* part  = ws + 4096;     // 32*8*8*256 = 524288 floats  (~2.1 MB total)

  k_fused<<<dim3(8, B_), 512, 0, stream>>>(x, query, Wkv, bkv, Wq, bq, stats, part);
  k_tail <<<B_,          512, 0, stream>>>(part, stats, Wkv, bkv, Wfc, bfc, out);
}

// Round 5
// 273.452 us; speedup vs baseline: 1.0729x; 1.0729x over previous
//
#include <hip/hip_runtime.h>
#include <hip/hip_bf16.h>

#define B_     32
#define C_     256
#define T_     4096
#define NH_    8
#define DH_    64

__global__ __launch_bounds__(256) void k_prep(
    const float* __restrict__ query, const float* __restrict__ Wkv,
    const float* __restrict__ bkv, const float* __restrict__ Wq,
    const float* __restrict__ bq, float* __restrict__ qWt,
    float* __restrict__ qb) {
  const int n = blockIdx.x;
  const int b = blockIdx.y;
  const int t = threadIdx.x;
  __shared__ float qrow_s[C_];
  __shared__ float psum[4 * 64];
  __shared__ float qsh[64];
  __shared__ float pb_s[64];

  qrow_s[t] = query[(size_t)b * C_ + t];
  __syncthreads();

  {
    const int d = t & 63, ch = t >> 6;
    const float* wrow = Wq + (size_t)(n * DH_ + d) * C_ + ch * 64;
    const float* qr = qrow_s + ch * 64;
    float s = 0.f;
    #pragma unroll
    for (int c = 0; c < 64; c += 4) {
      float4 w = *(const float4*)(wrow + c);
      s += w.x * qr[c] + w.y * qr[c + 1] + w.z * qr[c + 2] + w.w * qr[c + 3];
    }
    psum[ch * 64 + d] = s;
  }
  __syncthreads();
  if (t < 64)
    qsh[t] = bq[n * DH_ + t] + psum[t] + psum[64 + t] + psum[128 + t] + psum[192 + t];
  __syncthreads();

  const float scale = 0.125f;
  {
    const float* wk = Wkv + (size_t)(n * DH_) * C_ + t;
    float acc = 0.f;
    #pragma unroll 8
    for (int dd = 0; dd < DH_; ++dd) acc += qsh[dd] * wk[(size_t)dd * C_];
    qWt[((size_t)b * C_ + t) * NH_ + n] = acc * scale;
  }
  if (t < 64) pb_s[t] = qsh[t] * bkv[n * DH_ + t];
  __syncthreads();
  if (t == 0) {
    float s = 0.f;
    #pragma unroll 8
    for (int dd = 0; dd < 64; ++dd) s += pb_s[dd];
    qb[b * NH_ + n] = s * scale;
  }
}

// logits v3: occupancy fix. grid (32 jt, B_) = 1024 blocks x 256 thr
// (4 blocks/CU, 16 waves/CU). Block = 128-j segment, full C.
// Wave th (channel quarter) x lane tj (j-pair). Quarter partials combined
// through padded LDS (pitch 17: conflict-free). Wave 0 writes lgraw +
// per-segment LSE stats (m, sumexp).
__global__ __launch_bounds__(256, 4) void k_logits(
    const float* __restrict__ x, const float* __restrict__ qWt,
    const float* __restrict__ qbv, float* __restrict__ lgraw,
    float* __restrict__ stats) {
  const int jt = blockIdx.x;       // 0..31
  const int b  = blockIdx.y;
  const int t  = threadIdx.x;
  const int tj = t & 63;
  const int th = t >> 6;           // channel quarter, wave-uniform
  __shared__ float qws[C_ * NH_];  // 8 KB, scaled qWt[c][n]
  __shared__ float red[4][64][17]; // 17.4 KB padded partials

  {
    const float* src = qWt + (size_t)b * (C_ * NH_);
    *(float4*)&qws[t * 4] = *(const float4*)(src + t * 4);
    *(float4*)&qws[1024 + t * 4] = *(const float4*)(src + 1024 + t * 4);
  }
  __syncthreads();

  const int j = jt * 128 + tj * 2;
  const float* xb = x + ((size_t)b * C_ + th * 64) * T_ + j;

  float acc0[NH_], acc1[NH_];
  #pragma unroll
  for (int n = 0; n < NH_; ++n) {
    const float init = (th == 0) ? qbv[b * NH_ + n] : 0.f;
    acc0[n] = init; acc1[n] = init;
  }

  for (int c0 = 0; c0 < 64; c0 += 8) {
    float2 xv[8];
    #pragma unroll
    for (int cc = 0; cc < 8; ++cc)
      xv[cc] = *(const float2*)(xb + (size_t)(c0 + cc) * T_);
    #pragma unroll
    for (int cc = 0; cc < 8; ++cc) {
      const float4 w0 = *(const float4*)(qws + (th * 64 + c0 + cc) * 8);
      const float4 w1 = *(const float4*)(qws + (th * 64 + c0 + cc) * 8 + 4);
      acc0[0] += w0.x * xv[cc].x; acc1[0] += w0.x * xv[cc].y;
      acc0[1] += w0.y * xv[cc].x; acc1[1] += w0.y * xv[cc].y;
      acc0[2] += w0.z * xv[cc].x; acc1[2] += w0.z * xv[cc].y;
      acc0[3] += w0.w * xv[cc].x; acc1[3] += w0.w * xv[cc].y;
      acc0[4] += w1.x * xv[cc].x; acc1[4] += w1.x * xv[cc].y;
      acc0[5] += w1.y * xv[cc].x; acc1[5] += w1.y * xv[cc].y;
      acc0[6] += w1.z * xv[cc].x; acc1[6] += w1.z * xv[cc].y;
      acc0[7] += w1.w * xv[cc].x; acc1[7] += w1.w * xv[cc].y;
    }
  }

  if (th != 0) {
    float* r = &red[th][tj][0];
    #pragma unroll
    for (int n = 0; n < NH_; ++n) { r[n] = acc0[n]; r[8 + n] = acc1[n]; }
  }
  __syncthreads();
  if (th == 0) {
    #pragma unroll
    for (int q = 1; q < 4; ++q) {
      const float* r = &red[q][tj][0];
      #pragma unroll
      for (int n = 0; n < NH_; ++n) { acc0[n] += r[n]; acc1[n] += r[8 + n]; }
    }
    float* lg = lgraw + ((size_t)b * NH_) * T_ + j;
    #pragma unroll
    for (int n = 0; n < NH_; ++n) {
      float2 o; o.x = acc0[n]; o.y = acc1[n];
      *(float2*)(lg + (size_t)n * T_) = o;
    }
    // per-segment stats over this wave's 128 j
    float Mv[NH_], Sv[NH_];
    #pragma unroll
    for (int n = 0; n < NH_; ++n) {
      float mv = fmaxf(acc0[n], acc1[n]);
      #pragma unroll
      for (int o = 32; o >= 1; o >>= 1) mv = fmaxf(mv, __shfl_xor(mv, o));
      Mv[n] = mv;
    }
    #pragma unroll
    for (int n = 0; n < NH_; ++n) {
      float sv = expf(acc0[n] - Mv[n]) + expf(acc1[n] - Mv[n]);
      #pragma unroll
      for (int o = 32; o >= 1; o >>= 1) sv += __shfl_xor(sv, o);
      Sv[n] = sv;
    }
    if (tj == 0) {
      #pragma unroll
      for (int n = 0; n < NH_; ++n) {
        float2 o; o.x = Mv[n]; o.y = Sv[n];
        *(float2*)(stats + ((size_t)(b * NH_ + n) * 32 + jt) * 2) = o;
      }
    }
  }
}

// xattn (round-2 structure, 32-segment stats): grid (32 jt, B_) x 256.
// part[b][jt=32][n=8][c=256]
#define BJ_  128
#define BJS_ 32
#define XPITCH_ 33
__global__ __launch_bounds__(256, 4) void k_xattn(
    const float* __restrict__ x, const float* __restrict__ lgraw,
    const float* __restrict__ stats, float* __restrict__ part) {
  const int jt = blockIdx.x;
  const int b  = blockIdx.y;
  const int j0 = jt * BJ_;
  const int t  = threadIdx.x;
  __shared__ float xs[C_ * XPITCH_];
  __shared__ float a_lds[NH_][BJS_];
  __shared__ float Msh[NH_];
  __shared__ float Sish[NH_];

  if (t < NH_) {
    const float* st = stats + (size_t)(b * NH_ + t) * 64;
    float M = -3.4e38f;
    #pragma unroll
    for (int k = 0; k < 32; ++k) M = fmaxf(M, st[k * 2]);
    float S = 0.f;
    #pragma unroll
    for (int k = 0; k < 32; ++k) S += st[k * 2 + 1] * expf(st[k * 2] - M);
    Msh[t] = M; Sish[t] = 1.0f / S;
  }

  const float* xb  = x + (size_t)b * C_ * T_;
  const float* lgb = lgraw + (size_t)b * NH_ * T_ + j0;

  float acc[NH_];
  #pragma unroll
  for (int n = 0; n < NH_; ++n) acc[n] = 0.f;

  const int cr = t >> 3;
  const int jc = (t & 7) * 4;
  const int an = t >> 5;
  const int aj = t & 31;

  for (int sIt = 0; sIt < BJ_ / BJS_; ++sIt) {
    const int js = sIt * BJS_;
    __syncthreads();   // first iter also orders Msh/Sish
    #pragma unroll
    for (int p = 0; p < 8; ++p) {
      const int c = cr + p * 32;
      float4 vv = *(const float4*)(xb + (size_t)c * T_ + j0 + js + jc);
      float* dst = &xs[c * XPITCH_ + jc];
      dst[0] = vv.x; dst[1] = vv.y; dst[2] = vv.z; dst[3] = vv.w;
    }
    {
      const float lv = lgb[(size_t)an * T_ + js + aj];
      a_lds[an][aj] = expf(lv - Msh[an]) * Sish[an];
    }
    __syncthreads();
    const float* xr = &xs[t * XPITCH_];
    #pragma unroll 4
    for (int jj = 0; jj < BJS_; ++jj) {
      const float xv = xr[jj];
      #pragma unroll
      for (int n = 0; n < NH_; ++n)
        acc[n] += a_lds[n][jj] * xv;   // broadcast LDS read
    }
  }

  float* pb = part + ((size_t)b * 32 + jt) * (NH_ * C_);
  #pragma unroll
  for (int n = 0; n < NH_; ++n) pb[n * C_ + t] = acc[n];
}

// tail: reduce part (already softmax-normalized) + v-projection + fc.
__global__ __launch_bounds__(512) void k_tail(
    const float* __restrict__ part, const float* __restrict__ Wkv,
    const float* __restrict__ bkv, const float* __restrict__ Wfc,
    const float* __restrict__ bfc, float* __restrict__ out) {
  const int b = blockIdx.x;
  const int t = threadIdx.x;
  __shared__ float xa_s[NH_ * C_];
  __shared__ float ov_s[512];

  #pragma unroll
  for (int r = 0; r < 4; ++r) {
    const int idx = r * 512 + t;          // 0..2047 -> (n, c)
    const float* pb = part + (size_t)b * 32 * (NH_ * C_) + idx;
    float s = 0.f;
    #pragma unroll
    for (int k = 0; k < 32; ++k) s += pb[(size_t)k * NH_ * C_];
    xa_s[idx] = s;
  }
  __syncthreads();

  {
    const int o = t;                                // 0..511
    const float* wrow = Wkv + (size_t)(512 + o) * C_;
    const float* xa = &xa_s[(o >> 6) * C_];
    float s = bkv[512 + o];
    #pragma unroll 8
    for (int c = 0; c < C_; c += 4) {
      float4 w = *(const float4*)(wrow + c);
      s += w.x * xa[c] + w.y * xa[c + 1] + w.z * xa[c + 2] + w.w * xa[c + 3];
    }
    ov_s[o] = s;
  }
  __syncthreads();

  if (t < 256) {
    const float* wrow = Wfc + (size_t)t * 512;
    float s = bfc[t];
    #pragma unroll 8
    for (int o = 0; o < 512; o += 4) {
      float4 w = *(const float4*)(wrow + o);
      s += w.x * ov_s[o] + w.y * ov_s[o + 1] + w.z * ov_s[o + 2] + w.w * ov_s[o + 3];
    }
    out[(size_t)b * 256 + t] = fmaxf(s, 0.f);
  }
}

extern "C" void kernel_launch(void* const* d_in, const int* in_sizes, int n_in,
                              void* d_out, int out_size, void* d_ws, size_t ws_size,
                              hipStream_t stream) {
  const float* x     = (const float*)d_in[0];
  const float* query = (const float*)d_in[1];
  const float* Wkv   = (const float*)d_in[2];
  const float* bkv   = (const float*)d_in[3];
  const float* Wq    = (const float*)d_in[4];
  const float* bq    = (const float*)d_in[5];
  const float* Wfc   = (const float*)d_in[6];
  const float* bfc   = (const float*)d_in[7];
  float* out = (float*)d_out;
  float* ws  = (float*)d_ws;

  float* qWt   = ws;                   // 65536 floats
  float* qb    = ws + 65536;           // 256 (pad 512)
  float* stats = ws + 66048;           // 32*8*32*2 = 16384
  float* lgraw = ws + 82432;           // 32*8*4096 = 1048576
  float* part  = ws + 1131008;         // 32*32*8*256 = 2097152
  // total ~3.23 M floats = 12.9 MB

  k_prep   <<<dim3(NH_, B_), 256, 0, stream>>>(query, Wkv, bkv, Wq, bq, qWt, qb);
  k_logits <<<dim3(32, B_),  256, 0, stream>>>(x, qWt, qb, lgraw, stats);
  k_xattn  <<<dim3(32, B_),  256, 0, stream>>>(x, lgraw, stats, part);
  k_tail   <<<B_,            512, 0, stream>>>(part, Wkv, bkv, Wfc, bfc, out);
}

// Round 6
// 255.633 us; speedup vs baseline: 1.1477x; 1.0697x over previous
//
#include <hip/hip_runtime.h>
#include <hip/hip_bf16.h>

#define B_     32
#define C_     256
#define T_     4096
#define NH_    8
#define DH_    64

__global__ __launch_bounds__(256) void k_prep(
    const float* __restrict__ query, const float* __restrict__ Wkv,
    const float* __restrict__ bkv, const float* __restrict__ Wq,
    const float* __restrict__ bq, float* __restrict__ qWt,
    float* __restrict__ qb) {
  const int n = blockIdx.x;
  const int b = blockIdx.y;
  const int t = threadIdx.x;
  __shared__ float qrow_s[C_];
  __shared__ float psum[4 * 64];
  __shared__ float qsh[64];
  __shared__ float pb_s[64];

  qrow_s[t] = query[(size_t)b * C_ + t];
  __syncthreads();

  {
    const int d = t & 63, ch = t >> 6;
    const float* wrow = Wq + (size_t)(n * DH_ + d) * C_ + ch * 64;
    const float* qr = qrow_s + ch * 64;
    float s = 0.f;
    #pragma unroll
    for (int c = 0; c < 64; c += 4) {
      float4 w = *(const float4*)(wrow + c);
      s += w.x * qr[c] + w.y * qr[c + 1] + w.z * qr[c + 2] + w.w * qr[c + 3];
    }
    psum[ch * 64 + d] = s;
  }
  __syncthreads();
  if (t < 64)
    qsh[t] = bq[n * DH_ + t] + psum[t] + psum[64 + t] + psum[128 + t] + psum[192 + t];
  __syncthreads();

  const float scale = 0.125f;
  {
    const float* wk = Wkv + (size_t)(n * DH_) * C_ + t;
    float acc = 0.f;
    #pragma unroll 8
    for (int dd = 0; dd < DH_; ++dd) acc += qsh[dd] * wk[(size_t)dd * C_];
    qWt[((size_t)b * C_ + t) * NH_ + n] = acc * scale;
  }
  if (t < 64) pb_s[t] = qsh[t] * bkv[n * DH_ + t];
  __syncthreads();
  if (t == 0) {
    float s = 0.f;
    #pragma unroll 8
    for (int dd = 0; dd < 64; ++dd) s += pb_s[dd];
    qb[b * NH_ + n] = s * scale;
  }
}

// Fused logits + weighted-x partials, occupancy-first.
// grid (32 jt, B_) = 1024 blocks x 256 thr, ~29.5 KB LDS -> 4-5 blocks/CU.
// Phase 1: logits for 128-j segment (4 channel-quarter waves, combined via
// scratch), per-segment LSE stats + a_w[n][j] = exp(l - m_seg) in LDS.
// Phase 2: part[n][c] = sum_j a_w * x[c,j], x re-read from same-XCD L2.
// scratch (4352 floats) is red[4][64][17] in phase 1, xs[256][17] in phase 2.
#define SCR_ 4352
__global__ __launch_bounds__(256, 4) void k_fused(
    const float* __restrict__ x, const float* __restrict__ qWt,
    const float* __restrict__ qbv, float* __restrict__ stats,
    float* __restrict__ part) {
  const int jt = blockIdx.x;       // 0..31
  const int b  = blockIdx.y;
  const int t  = threadIdx.x;
  const int tj = t & 63;
  const int th = t >> 6;           // channel quarter, wave-uniform
  __shared__ float qws[C_ * NH_];      // 8 KB
  __shared__ float scratch[SCR_];      // 17 KB (red / xs)
  __shared__ float a_w[NH_][128];      // 4 KB

  {
    const float* src = qWt + (size_t)b * (C_ * NH_);
    *(float4*)&qws[t * 4]        = *(const float4*)(src + t * 4);
    *(float4*)&qws[1024 + t * 4] = *(const float4*)(src + 1024 + t * 4);
  }
  __syncthreads();

  // ---- phase 1: logits ----
  const int j = jt * 128 + tj * 2;
  const float* xb = x + ((size_t)b * C_ + th * 64) * T_ + j;

  float acc0[NH_], acc1[NH_];
  #pragma unroll
  for (int n = 0; n < NH_; ++n) {
    const float init = (th == 0) ? qbv[b * NH_ + n] : 0.f;
    acc0[n] = init; acc1[n] = init;
  }

  for (int c0 = 0; c0 < 64; c0 += 8) {
    float2 xv[8];
    #pragma unroll
    for (int cc = 0; cc < 8; ++cc)
      xv[cc] = *(const float2*)(xb + (size_t)(c0 + cc) * T_);
    #pragma unroll
    for (int cc = 0; cc < 8; ++cc) {
      const float4 w0 = *(const float4*)(qws + (th * 64 + c0 + cc) * 8);
      const float4 w1 = *(const float4*)(qws + (th * 64 + c0 + cc) * 8 + 4);
      acc0[0] += w0.x * xv[cc].x; acc1[0] += w0.x * xv[cc].y;
      acc0[1] += w0.y * xv[cc].x; acc1[1] += w0.y * xv[cc].y;
      acc0[2] += w0.z * xv[cc].x; acc1[2] += w0.z * xv[cc].y;
      acc0[3] += w0.w * xv[cc].x; acc1[3] += w0.w * xv[cc].y;
      acc0[4] += w1.x * xv[cc].x; acc1[4] += w1.x * xv[cc].y;
      acc0[5] += w1.y * xv[cc].x; acc1[5] += w1.y * xv[cc].y;
      acc0[6] += w1.z * xv[cc].x; acc1[6] += w1.z * xv[cc].y;
      acc0[7] += w1.w * xv[cc].x; acc1[7] += w1.w * xv[cc].y;
    }
  }

  if (th != 0) {
    float* r = &scratch[(th * 64 + tj) * 17];
    #pragma unroll
    for (int n = 0; n < NH_; ++n) { r[n] = acc0[n]; r[8 + n] = acc1[n]; }
  }
  __syncthreads();
  if (th == 0) {
    #pragma unroll
    for (int q = 1; q < 4; ++q) {
      const float* r = &scratch[(q * 64 + tj) * 17];
      #pragma unroll
      for (int n = 0; n < NH_; ++n) { acc0[n] += r[n]; acc1[n] += r[8 + n]; }
    }
    // segment stats + unnormalized weights
    float Mv[NH_];
    #pragma unroll
    for (int n = 0; n < NH_; ++n) {
      float mv = fmaxf(acc0[n], acc1[n]);
      #pragma unroll
      for (int o = 32; o >= 1; o >>= 1) mv = fmaxf(mv, __shfl_xor(mv, o));
      Mv[n] = mv;
    }
    float Sv[NH_];
    #pragma unroll
    for (int n = 0; n < NH_; ++n) {
      const float e0 = expf(acc0[n] - Mv[n]);
      const float e1 = expf(acc1[n] - Mv[n]);
      a_w[n][tj * 2]     = e0;
      a_w[n][tj * 2 + 1] = e1;
      float sv = e0 + e1;
      #pragma unroll
      for (int o = 32; o >= 1; o >>= 1) sv += __shfl_xor(sv, o);
      Sv[n] = sv;
    }
    if (tj == 0) {
      #pragma unroll
      for (int n = 0; n < NH_; ++n) {
        float2 o; o.x = Mv[n]; o.y = Sv[n];
        *(float2*)(stats + ((size_t)(b * NH_ + n) * 32 + jt) * 2) = o;
      }
    }
  }
  // waves 1-3 wait at the loop-top barrier; wave 0 arrives only after it is
  // done reading scratch -> safe to overwrite scratch after that barrier.

  // ---- phase 2: part[n][c] = sum_j a_w[n][j] * x[c][j] ----
  const float* xb2 = x + (size_t)b * C_ * T_ + jt * 128;
  const int cr = t >> 2;          // staging row 0..63
  const int jc = (t & 3) * 4;     // staging j offset 0/4/8/12
  float acc[NH_];
  #pragma unroll
  for (int n = 0; n < NH_; ++n) acc[n] = 0.f;

  for (int sIt = 0; sIt < 8; ++sIt) {
    const int js = sIt * 16;
    __syncthreads();
    #pragma unroll
    for (int p = 0; p < 4; ++p) {
      const int c = cr + p * 64;
      float4 vv = *(const float4*)(xb2 + (size_t)c * T_ + js + jc);
      float* dst = &scratch[c * 17 + jc];
      dst[0] = vv.x; dst[1] = vv.y; dst[2] = vv.z; dst[3] = vv.w;
    }
    __syncthreads();
    const float* xr = &scratch[t * 17];
    #pragma unroll
    for (int jj = 0; jj < 16; ++jj) {
      const float xv = xr[jj];
      const int jg = js + jj;     // wave-uniform -> a_w reads are broadcasts
      #pragma unroll
      for (int n = 0; n < NH_; ++n)
        acc[n] += a_w[n][jg] * xv;
    }
  }

  float* pb = part + ((size_t)b * 32 + jt) * (NH_ * C_);
  #pragma unroll
  for (int n = 0; n < NH_; ++n) pb[n * C_ + t] = acc[n];
}

// LSE-combine + reduce + v-projection: grid (NH_, B_) x 256 (r2-proven shape).
__global__ __launch_bounds__(256) void k_out2(
    const float* __restrict__ part, const float* __restrict__ stats,
    const float* __restrict__ Wkv, const float* __restrict__ bkv,
    float* __restrict__ outvG) {
  const int n = blockIdx.x;
  const int b = blockIdx.y;
  const int t = threadIdx.x;
  __shared__ float sc[32];
  __shared__ float xa[C_];
  __shared__ float psum[4][64];

  if (t < 32) {
    const float* st = stats + (size_t)(b * NH_ + n) * 64;
    const float mk = st[2 * t], sk = st[2 * t + 1];
    float M = mk;
    #pragma unroll
    for (int o = 16; o >= 1; o >>= 1) M = fmaxf(M, __shfl_xor(M, o));
    const float e = expf(mk - M);
    float S = sk * e;
    #pragma unroll
    for (int o = 16; o >= 1; o >>= 1) S += __shfl_xor(S, o);
    sc[t] = e / S;
  }
  __syncthreads();

  {
    const float* pb = part + (size_t)b * 32 * (NH_ * C_) + n * C_ + t;
    float s = 0.f;
    #pragma unroll
    for (int k = 0; k < 32; ++k) s += sc[k] * pb[(size_t)k * (NH_ * C_)];
    xa[t] = s;
  }
  __syncthreads();

  {
    const int d = t & 63, q = t >> 6;
    const float* wrow = Wkv + (size_t)(512 + n * 64 + d) * C_ + q * 64;
    const float* xq = xa + q * 64;
    float s = 0.f;
    #pragma unroll
    for (int c = 0; c < 64; c += 4) {
      float4 w = *(const float4*)(wrow + c);
      s += w.x * xq[c] + w.y * xq[c + 1] + w.z * xq[c + 2] + w.w * xq[c + 3];
    }
    psum[q][d] = s;
  }
  __syncthreads();
  if (t < 64)
    outvG[(size_t)b * 512 + n * 64 + t] =
        bkv[512 + n * 64 + t] + psum[0][t] + psum[1][t] + psum[2][t] + psum[3][t];
}

__global__ __launch_bounds__(256) void k_fc(
    const float* __restrict__ outvG, const float* __restrict__ Wfc,
    const float* __restrict__ bfc, float* __restrict__ out) {
  __shared__ float ov[512];
  const int b = blockIdx.x;
  const int t = threadIdx.x;
  ov[t] = outvG[(size_t)b * 512 + t];
  ov[256 + t] = outvG[(size_t)b * 512 + 256 + t];
  __syncthreads();

  const float* wrow = Wfc + (size_t)t * 512;
  float s = bfc[t];
  #pragma unroll 8
  for (int o = 0; o < 512; o += 4) {
    float4 w = *(const float4*)(wrow + o);
    s += w.x * ov[o] + w.y * ov[o + 1] + w.z * ov[o + 2] + w.w * ov[o + 3];
  }
  out[(size_t)b * 256 + t] = fmaxf(s, 0.f);
}

extern "C" void kernel_launch(void* const* d_in, const int* in_sizes, int n_in,
                              void* d_out, int out_size, void* d_ws, size_t ws_size,
                              hipStream_t stream) {
  const float* x     = (const float*)d_in[0];
  const float* query = (const float*)d_in[1];
  const float* Wkv   = (const float*)d_in[2];
  const float* bkv   = (const float*)d_in[3];
  const float* Wq    = (const float*)d_in[4];
  const float* bq    = (const float*)d_in[5];
  const float* Wfc   = (const float*)d_in[6];
  const float* bfc   = (const float*)d_in[7];
  float* out = (float*)d_out;
  float* ws  = (float*)d_ws;

  float* qWt   = ws;                   // 65536 floats
  float* qb    = ws + 65536;           // 256 (pad 512)
  float* stats = ws + 66048;           // 32*8*32*2 = 16384
  float* part  = ws + 82432;           // 32*32*8*256 = 2097152
  float* outvG = ws + 2179584;         // 16384
  // total ~2.2 M floats = 8.8 MB

  k_prep  <<<dim3(NH_, B_), 256, 0, stream>>>(query, Wkv, bkv, Wq, bq, qWt, qb);
  k_fused <<<dim3(32, B_),  256, 0, stream>>>(x, qWt, qb, stats, part);
  k_out2  <<<dim3(NH_, B_), 256, 0, stream>>>(part, stats, Wkv, bkv, outvG);
  k_fc    <<<B_,            256, 0, stream>>>(outvG, Wfc, bfc, out);
}

// Round 9
// 253.977 us; speedup vs baseline: 1.1551x; 1.0065x over previous
//
#include <hip/hip_runtime.h>
#include <hip/hip_bf16.h>

#define B_     32
#define C_     256
#define T_     4096
#define NH_    8
#define DH_    64

__global__ __launch_bounds__(256) void k_prep(
    const float* __restrict__ query, const float* __restrict__ Wkv,
    const float* __restrict__ bkv, const float* __restrict__ Wq,
    const float* __restrict__ bq, float* __restrict__ qWt,
    float* __restrict__ qb) {
  const int n = blockIdx.x;
  const int b = blockIdx.y;
  const int t = threadIdx.x;
  __shared__ float qrow_s[C_];
  __shared__ float psum[4 * 64];
  __shared__ float qsh[64];
  __shared__ float pb_s[64];

  qrow_s[t] = query[(size_t)b * C_ + t];
  __syncthreads();

  {
    const int d = t & 63, ch = t >> 6;
    const float* wrow = Wq + (size_t)(n * DH_ + d) * C_ + ch * 64;
    const float* qr = qrow_s + ch * 64;
    float s = 0.f;
    #pragma unroll
    for (int c = 0; c < 64; c += 4) {
      float4 w = *(const float4*)(wrow + c);
      s += w.x * qr[c] + w.y * qr[c + 1] + w.z * qr[c + 2] + w.w * qr[c + 3];
    }
    psum[ch * 64 + d] = s;
  }
  __syncthreads();
  if (t < 64)
    qsh[t] = bq[n * DH_ + t] + psum[t] + psum[64 + t] + psum[128 + t] + psum[192 + t];
  __syncthreads();

  const float scale = 0.125f;
  {
    const float* wk = Wkv + (size_t)(n * DH_) * C_ + t;
    float acc = 0.f;
    #pragma unroll 8
    for (int dd = 0; dd < DH_; ++dd) acc += qsh[dd] * wk[(size_t)dd * C_];
    qWt[((size_t)b * C_ + t) * NH_ + n] = acc * scale;
  }
  if (t < 64) pb_s[t] = qsh[t] * bkv[n * DH_ + t];
  __syncthreads();
  if (t == 0) {
    float s = 0.f;
    #pragma unroll 8
    for (int dd = 0; dd < 64; ++dd) s += pb_s[dd];
    qb[b * NH_ + n] = s * scale;
  }
}

// Fused logits + weighted-x partials.
// grid (32 jt, B_) = 1024 blocks x 256 thr, ~34 KB LDS -> 4 blocks/CU.
// Phase 1: identical to round 6 (ran OK). Phase 2: round-6 ownership
// (thread t = channel t, all 128 j, merge-free epilogue) with ONLY the LDS
// access shapes changed: a_w j-major [128][12] -> 2 broadcast b128 per j
// (was 8 serialized b32); xs staged/read as aligned float4 on pitch 20.
#define SCR_ 5120
__global__ __launch_bounds__(256, 4) void k_fused(
    const float* __restrict__ x, const float* __restrict__ qWt,
    const float* __restrict__ qbv, float* __restrict__ stats,
    float* __restrict__ part) {
  const int jt = blockIdx.x;       // 0..31
  const int b  = blockIdx.y;
  const int t  = threadIdx.x;
  const int tj = t & 63;
  const int th = t >> 6;           // wave id / channel quarter
  __shared__ float qws[C_ * NH_];                 // 8 KB
  __shared__ __align__(16) float scratch[SCR_];   // 20 KB (red / xs)
  __shared__ __align__(16) float a_w[128][12];    // 6 KB, j-major

  {
    const float* src = qWt + (size_t)b * (C_ * NH_);
    *(float4*)&qws[t * 4]        = *(const float4*)(src + t * 4);
    *(float4*)&qws[1024 + t * 4] = *(const float4*)(src + 1024 + t * 4);
  }
  __syncthreads();

  // ---- phase 1: logits (unchanged from round 6) ----
  const int j = jt * 128 + tj * 2;
  const float* xb = x + ((size_t)b * C_ + th * 64) * T_ + j;

  float acc0[NH_], acc1[NH_];
  #pragma unroll
  for (int n = 0; n < NH_; ++n) {
    const float init = (th == 0) ? qbv[b * NH_ + n] : 0.f;
    acc0[n] = init; acc1[n] = init;
  }

  for (int c0 = 0; c0 < 64; c0 += 8) {
    float2 xv[8];
    #pragma unroll
    for (int cc = 0; cc < 8; ++cc)
      xv[cc] = *(const float2*)(xb + (size_t)(c0 + cc) * T_);
    #pragma unroll
    for (int cc = 0; cc < 8; ++cc) {
      const float4 w0 = *(const float4*)(qws + (th * 64 + c0 + cc) * 8);
      const float4 w1 = *(const float4*)(qws + (th * 64 + c0 + cc) * 8 + 4);
      acc0[0] += w0.x * xv[cc].x; acc1[0] += w0.x * xv[cc].y;
      acc0[1] += w0.y * xv[cc].x; acc1[1] += w0.y * xv[cc].y;
      acc0[2] += w0.z * xv[cc].x; acc1[2] += w0.z * xv[cc].y;
      acc0[3] += w0.w * xv[cc].x; acc1[3] += w0.w * xv[cc].y;
      acc0[4] += w1.x * xv[cc].x; acc1[4] += w1.x * xv[cc].y;
      acc0[5] += w1.y * xv[cc].x; acc1[5] += w1.y * xv[cc].y;
      acc0[6] += w1.z * xv[cc].x; acc1[6] += w1.z * xv[cc].y;
      acc0[7] += w1.w * xv[cc].x; acc1[7] += w1.w * xv[cc].y;
    }
  }

  if (th != 0) {
    float* r = &scratch[(th * 64 + tj) * 17];
    #pragma unroll
    for (int n = 0; n < NH_; ++n) { r[n] = acc0[n]; r[8 + n] = acc1[n]; }
  }
  __syncthreads();
  if (th == 0) {
    #pragma unroll
    for (int q = 1; q < 4; ++q) {
      const float* r = &scratch[(q * 64 + tj) * 17];
      #pragma unroll
      for (int n = 0; n < NH_; ++n) { acc0[n] += r[n]; acc1[n] += r[8 + n]; }
    }
    float Mv[NH_];
    #pragma unroll
    for (int n = 0; n < NH_; ++n) {
      float mv = fmaxf(acc0[n], acc1[n]);
      #pragma unroll
      for (int o = 32; o >= 1; o >>= 1) mv = fmaxf(mv, __shfl_xor(mv, o));
      Mv[n] = mv;
    }
    float e0[NH_], e1[NH_], Sv[NH_];
    #pragma unroll
    for (int n = 0; n < NH_; ++n) {
      e0[n] = expf(acc0[n] - Mv[n]);
      e1[n] = expf(acc1[n] - Mv[n]);
      float sv = e0[n] + e1[n];
      #pragma unroll
      for (int o = 32; o >= 1; o >>= 1) sv += __shfl_xor(sv, o);
      Sv[n] = sv;
    }
    // j-major weight table (b128 rows)
    *(float4*)&a_w[tj * 2][0]     = make_float4(e0[0], e0[1], e0[2], e0[3]);
    *(float4*)&a_w[tj * 2][4]     = make_float4(e0[4], e0[5], e0[6], e0[7]);
    *(float4*)&a_w[tj * 2 + 1][0] = make_float4(e1[0], e1[1], e1[2], e1[3]);
    *(float4*)&a_w[tj * 2 + 1][4] = make_float4(e1[4], e1[5], e1[6], e1[7]);
    if (tj == 0) {
      #pragma unroll
      for (int n = 0; n < NH_; ++n) {
        float2 o; o.x = Mv[n]; o.y = Sv[n];
        *(float2*)(stats + ((size_t)(b * NH_ + n) * 32 + jt) * 2) = o;
      }
    }
  }
  // loop-top barrier below orders a_w writes / scratch reuse.

  // ---- phase 2: part[n][c] = sum_j a_w[j][n] * x[c][j] ----
  const float* xb2 = x + (size_t)b * C_ * T_ + jt * 128;
  const int cr = t >> 2;          // staging row 0..63
  const int jc = (t & 3) * 4;     // staging col 0/4/8/12

  float acc[NH_];
  #pragma unroll
  for (int n = 0; n < NH_; ++n) acc[n] = 0.f;

  for (int sIt = 0; sIt < 8; ++sIt) {
    const int js = sIt * 16;
    __syncthreads();
    #pragma unroll
    for (int p = 0; p < 4; ++p) {
      const int c = cr + p * 64;
      float4 vv = *(const float4*)(xb2 + (size_t)c * T_ + js + jc);
      *(float4*)&scratch[c * 20 + jc] = vv;
    }
    __syncthreads();
    const float* xr = &scratch[t * 20];
    #pragma unroll
    for (int g = 0; g < 4; ++g) {
      const float4 xv4 = *(const float4*)&xr[g * 4];
      #pragma unroll
      for (int q = 0; q < 4; ++q) {
        const int jg = js + g * 4 + q;           // wave-uniform -> broadcast
        const float4 wlo = *(const float4*)&a_w[jg][0];
        const float4 whi = *(const float4*)&a_w[jg][4];
        const float xv = (q == 0) ? xv4.x : (q == 1) ? xv4.y
                       : (q == 2) ? xv4.z : xv4.w;
        acc[0] += wlo.x * xv; acc[1] += wlo.y * xv;
        acc[2] += wlo.z * xv; acc[3] += wlo.w * xv;
        acc[4] += whi.x * xv; acc[5] += whi.y * xv;
        acc[6] += whi.z * xv; acc[7] += whi.w * xv;
      }
    }
  }

  {
    float* pb = part + ((size_t)b * 32 + jt) * (NH_ * C_);
    #pragma unroll
    for (int n = 0; n < NH_; ++n) pb[n * C_ + t] = acc[n];
  }
}

// LSE-combine + reduce + v-projection: grid (NH_, B_) x 256.
__global__ __launch_bounds__(256) void k_out2(
    const float* __restrict__ part, const float* __restrict__ stats,
    const float* __restrict__ Wkv, const float* __restrict__ bkv,
    float* __restrict__ outvG) {
  const int n = blockIdx.x;
  const int b = blockIdx.y;
  const int t = threadIdx.x;
  __shared__ float sc[32];
  __shared__ float xa[C_];
  __shared__ float psum[4][64];

  if (t < 32) {
    const float* st = stats + (size_t)(b * NH_ + n) * 64;
    const float mk = st[2 * t], sk = st[2 * t + 1];
    float M = mk;
    #pragma unroll
    for (int o = 16; o >= 1; o >>= 1) M = fmaxf(M, __shfl_xor(M, o));
    const float e = expf(mk - M);
    float S = sk * e;
    #pragma unroll
    for (int o = 16; o >= 1; o >>= 1) S += __shfl_xor(S, o);
    sc[t] = e / S;
  }
  __syncthreads();

  {
    const float* pb = part + (size_t)b * 32 * (NH_ * C_) + n * C_ + t;
    float s = 0.f;
    #pragma unroll
    for (int k = 0; k < 32; ++k) s += sc[k] * pb[(size_t)k * (NH_ * C_)];
    xa[t] = s;
  }
  __syncthreads();

  {
    const int d = t & 63, q = t >> 6;
    const float* wrow = Wkv + (size_t)(512 + n * 64 + d) * C_ + q * 64;
    const float* xq = xa + q * 64;
    float s = 0.f;
    #pragma unroll
    for (int c = 0; c < 64; c += 4) {
      float4 w = *(const float4*)(wrow + c);
      s += w.x * xq[c] + w.y * xq[c + 1] + w.z * xq[c + 2] + w.w * xq[c + 3];
    }
    psum[q][d] = s;
  }
  __syncthreads();
  if (t < 64)
    outvG[(size_t)b * 512 + n * 64 + t] =
        bkv[512 + n * 64 + t] + psum[0][t] + psum[1][t] + psum[2][t] + psum[3][t];
}

__global__ __launch_bounds__(256) void k_fc(
    const float* __restrict__ outvG, const float* __restrict__ Wfc,
    const float* __restrict__ bfc, float* __restrict__ out) {
  __shared__ float ov[512];
  const int b = blockIdx.x;
  const int t = threadIdx.x;
  ov[t] = outvG[(size_t)b * 512 + t];
  ov[256 + t] = outvG[(size_t)b * 512 + 256 + t];
  __syncthreads();

  const float* wrow = Wfc + (size_t)t * 512;
  float s = bfc[t];
  #pragma unroll 8
  for (int o = 0; o < 512; o += 4) {
    float4 w = *(const float4*)(wrow + o);
    s += w.x * ov[o] + w.y * ov[o + 1] + w.z * ov[o + 2] + w.w * ov[o + 3];
  }
  out[(size_t)b * 256 + t] = fmaxf(s, 0.f);
}

extern "C" void kernel_launch(void* const* d_in, const int* in_sizes, int n_in,
                              void* d_out, int out_size, void* d_ws, size_t ws_size,
                              hipStream_t stream) {
  const float* x     = (const float*)d_in[0];
  const float* query = (const float*)d_in[1];
  const float* Wkv   = (const float*)d_in[2];
  const float* bkv   = (const float*)d_in[3];
  const float* Wq    = (const float*)d_in[4];
  const float* bq    = (const float*)d_in[5];
  const float* Wfc   = (const float*)d_in[6];
  const float* bfc   = (const float*)d_in[7];
  float* out = (float*)d_out;
  float* ws  = (float*)d_ws;

  float* qWt   = ws;                   // 65536 floats
  float* qb    = ws + 65536;           // 256 (pad 512)
  float* stats = ws + 66048;           // 32*8*32*2 = 16384
  float* part  = ws + 82432;           // 32*32*8*256 = 2097152
  float* outvG = ws + 2179584;         // 16384

  k_prep  <<<dim3(NH_, B_), 256, 0, stream>>>(query, Wkv, bkv, Wq, bq, qWt, qb);
  k_fused <<<dim3(32, B_),  256, 0, stream>>>(x, qWt, qb, stats, part);
  k_out2  <<<dim3(NH_, B_), 256, 0, stream>>>(part, stats, Wkv, bkv, outvG);
  k_fc    <<<B_,            256, 0, stream>>>(outvG, Wfc, bfc, out);
}